// Round 7
// baseline (108.677 us; speedup 1.0000x reference)
//
#include <hip/hip_runtime.h>
#include <math.h>

#define PI_F 3.14159f
#define STRD 69            // row stride: 66 used cols (-1..65 -> slots 0..66) + pad
#define SLICE3 (67 * 69)   // 67 rows (y=-1..65) * stride

typedef float f4 __attribute__((ext_vector_type(4)));  // for nontemporal stores

// ---------- Kernel 1: all per-(b,d) params, pre-folded for the sampler ----------
// 32 blocks x 256 thr. Block = (b, 32-d chunk). GEMV p=relu(pc@W_c+b_c) split-K
// over 4 waves, then heads with 8-lane split-K per d. Output par[(b<<8)+d] =
// {co*sc*32, si*sc*32, t0*32+31.5, t1*32+31.5}.
__global__ __launch_bounds__(256) void adaat_params_kernel(
    const float* __restrict__ para_code,
    const float* __restrict__ W_c, const float* __restrict__ b_c,
    const float* __restrict__ W_s, const float* __restrict__ b_s,
    const float* __restrict__ W_r, const float* __restrict__ b_r,
    const float* __restrict__ W_t, const float* __restrict__ b_t,
    float4* __restrict__ par) {
  const int bid = blockIdx.x;
  const int b = bid >> 3;
  const int dbase = (bid & 7) << 5;
  const int tid = threadIdx.x;
  __shared__ float redp[4][256];
  __shared__ float p_l[256];

  {
    const int wv = tid >> 6, ln = tid & 63;
    const float* pcb = para_code + (b << 8);
    float pcv = pcb[(wv << 6) | ln];
    float4 a4 = make_float4(0.f, 0.f, 0.f, 0.f);
#pragma unroll
    for (int kk = 0; kk < 64; ++kk) {
      float pk = __int_as_float(
          __builtin_amdgcn_readlane(__float_as_int(pcv), kk));
      const float4* Wrow = (const float4*)(W_c + (((wv << 6) + kk) << 8));
      float4 w4 = Wrow[ln];
      a4.x = fmaf(pk, w4.x, a4.x);
      a4.y = fmaf(pk, w4.y, a4.y);
      a4.z = fmaf(pk, w4.z, a4.z);
      a4.w = fmaf(pk, w4.w, a4.w);
    }
    ((float4*)&redp[wv][0])[ln] = a4;
  }
  __syncthreads();
  p_l[tid] = fmaxf(
      redp[0][tid] + redp[1][tid] + redp[2][tid] + redp[3][tid] + b_c[tid],
      0.0f);
  __syncthreads();

  const int dloc = tid >> 3;  // 0..31
  const int kc = tid & 7;     // k-chunk of 32
  const int d = dbase + dloc;
  float vs = 0.f, vr = 0.f, va = 0.f, vb = 0.f;
  const float2* W_t2 = (const float2*)W_t;
  const int k0 = kc << 5;
#pragma unroll 8
  for (int k = k0; k < k0 + 32; ++k) {
    float pk = p_l[k];
    vs = fmaf(pk, W_s[(k << 8) + d], vs);
    vr = fmaf(pk, W_r[(k << 8) + d], vr);
    float2 wt = W_t2[(k << 8) + d];
    va = fmaf(pk, wt.x, va);
    vb = fmaf(pk, wt.y, vb);
  }
#pragma unroll
  for (int off = 4; off > 0; off >>= 1) {
    vs += __shfl_xor(vs, off);
    vr += __shfl_xor(vr, off);
    va += __shfl_xor(va, off);
    vb += __shfl_xor(vb, off);
  }
  if (kc == 0) {
    vs += b_s[d];
    vr += b_r[d];
    va += b_t[2 * d];
    vb += b_t[2 * d + 1];
    float scl = 2.0f / (1.0f + expf(-vs));
    float ang = tanhf(vr) * PI_F;
    float sc32 = scl * 32.0f;
    float4 o;
    o.x = cosf(ang) * sc32;
    o.y = sinf(ang) * sc32;
    o.z = fmaf(tanhf(va), 32.0f, 31.5f);
    o.w = fmaf(tanhf(vb), 32.0f, 31.5f);
    par[(b << 8) + d] = o;
  }
}

// ---------- Kernel 2: warp + trilinear sample, pipelined across 2 planes ----------
// 512 blocks x 256 thr; XCD swizzle gives each XCD a contiguous 64-block range
// (slice working set ~2MB fits one XCD L2). LDS = 3 guard-ring slices (54.2KB).
__global__ __launch_bounds__(256, 2) void adaat_main_kernel(
    const float* __restrict__ fm,
    const float4* __restrict__ par,
    float* __restrict__ out) {
  const int i = blockIdx.x;
  const int bid = ((i & 7) << 6) | (i >> 3);  // XCD-contiguous remap
  const int b = bid >> 7;
  const int d0 = (bid & 127) << 1;
  const int d1 = d0 + 1;
  const int tid = threadIdx.x;

  __shared__ float sm[3 * SLICE3];

  // z geometry (exact reference formula sequence)
  float gz0 = 2.0f * (d0 * (1.0f / 255.0f)) - 1.0f;
  float izA = ((gz0 + 1.0f) * 256.0f - 1.0f) * 0.5f;
  float z0fA = floorf(izA);
  float wzA = izA - z0fA;
  int zA = (int)z0fA;
  float gz1 = 2.0f * (d1 * (1.0f / 255.0f)) - 1.0f;
  float izB = ((gz1 + 1.0f) * 256.0f - 1.0f) * 0.5f;
  float z0fB = floorf(izB);
  float wzB = izB - z0fB;
  int zB = (int)z0fB;
  int slB = zB - zA;  // ==1 for all even d0 (proven); guard anyway
  if (slB > 1) slB = 1;
  if (slB < 0) slB = 0;

  // prefetch 3 slices into regs (slice 2 last -> drains under plane-0 sampling)
  float4 pre[3][4];
  const float4* fmb = (const float4*)(fm + ((size_t)b << 20));
#pragma unroll
  for (int s = 0; s < 3; ++s) {
    int z = zA + s;
    if ((unsigned)z < 256u) {  // block-uniform branch
      const float4* src = fmb + ((size_t)z << 10);
#pragma unroll
      for (int k = 0; k < 4; ++k) pre[s][k] = src[(k << 8) + tid];
    } else {
#pragma unroll
      for (int k = 0; k < 4; ++k) pre[s][k] = make_float4(0.f, 0.f, 0.f, 0.f);
    }
  }

  // uniform param loads (scalar), issued early
  float4 p40 = par[(b << 8) + d0];
  float4 p41 = par[(b << 8) + d1];

  // zero guard ring of all 3 slices (no vmcnt dependency)
#pragma unroll
  for (int s = 0; s < 3; ++s) {
    float* smb = sm + s * SLICE3;
    if (tid < STRD) {
      smb[tid] = 0.0f;
      smb[65 * STRD + tid] = 0.0f;
      smb[66 * STRD + tid] = 0.0f;
    }
    int r = 1 + (tid >> 2);
    int q = tid & 3;
    int c = q ? (64 + q) : 0;
    smb[r * STRD + c] = 0.0f;
  }

  // stage slices 0,1 (waits only their 8 loads)
#pragma unroll
  for (int s = 0; s < 2; ++s) {
    float* smb = sm + s * SLICE3;
#pragma unroll
    for (int k = 0; k < 4; ++k) {
      int e = ((k << 8) + tid) << 2;
      int y = e >> 6, x0 = e & 63;
      int a = (y + 1) * STRD + x0 + 1;
      float4 v = pre[s][k];
      smb[a] = v.x; smb[a + 1] = v.y; smb[a + 2] = v.z; smb[a + 3] = v.w;
    }
  }
  __syncthreads();

  const float dgx = 2.0f / 63.0f;
  const int w0 = (tid & 15) << 2;
  const int h0 = tid >> 4;
  const float gx0 = w0 * dgx - 1.0f;

#pragma unroll
  for (int pl = 0; pl < 2; ++pl) {
    const float4 p4 = pl ? p41 : p40;
    const float co32 = p4.x;
    const float si32 = p4.y;
    const float wz = pl ? wzB : wzA;
    const float wzl0 = 1.0f - wz, wzl1 = wz;
    const float* smA = sm + ((pl ? slB : 0) * SLICE3);
    const float* smB = smA + SLICE3;
    float* outp = out + (((size_t)(b << 8) + d0 + pl) << 12);

    const float stx = co32 * dgx;
    const float sty = si32 * dgx;
    const float ixw = fmaf(co32, gx0, p4.z);
    const float iyw = fmaf(si32, gx0, p4.w);

#pragma unroll
    for (int j = 0; j < 4; ++j) {
      int h = (j << 4) + h0;
      float gy = h * dgx - 1.0f;
      float ix = fmaf(-si32, gy, ixw);
      float iy = fmaf(co32, gy, iyw);
      float rr[4];
#pragma unroll
      for (int q = 0; q < 4; ++q) {
        float x0f = floorf(ix), y0f = floorf(iy);
        float wx = ix - x0f, wy = iy - y0f;
        int xi = (int)x0f, yi = (int)y0f;
        int bx = min(max(xi, -1), 64);  // v_med3_i32
        int by = min(max(yi, -1), 64);
        float wxe = (bx == xi) ? wx : 0.0f;
        float wye = (by == yi) ? wy : 0.0f;
        float w11 = wye * wxe;
        float w10 = wye - w11;
        float w01 = wxe - w11;
        float w00 = (1.0f - wye) - w01;
        int base = (by + 1) * STRD + bx + 1;
        float accA = fmaf(smA[base], w00,
                     fmaf(smA[base + 1], w01,
                     fmaf(smA[base + STRD], w10, smA[base + STRD + 1] * w11)));
        float accB = fmaf(smB[base], w00,
                     fmaf(smB[base + 1], w01,
                     fmaf(smB[base + STRD], w10, smB[base + STRD + 1] * w11)));
        rr[q] = fmaf(wzl0, accA, wzl1 * accB);
        ix += stx;
        iy += sty;
      }
      f4 res;
      res.x = rr[0]; res.y = rr[1]; res.z = rr[2]; res.w = rr[3];
      __builtin_nontemporal_store(res, (f4*)outp + (j << 8) + tid);
    }

    if (pl == 0) {
      // stage slice 2 (its loads drained during plane-0 sampling)
      float* smb = sm + 2 * SLICE3;
#pragma unroll
      for (int k = 0; k < 4; ++k) {
        int e = ((k << 8) + tid) << 2;
        int y = e >> 6, x0 = e & 63;
        int a = (y + 1) * STRD + x0 + 1;
        float4 v = pre[2][k];
        smb[a] = v.x; smb[a + 1] = v.y; smb[a + 2] = v.z; smb[a + 3] = v.w;
      }
      __syncthreads();
    }
  }
}

extern "C" void kernel_launch(void* const* d_in, const int* in_sizes, int n_in,
                              void* d_out, int out_size, void* d_ws, size_t ws_size,
                              hipStream_t stream) {
  const float* fm        = (const float*)d_in[0];  // (4,256,64,64)
  const float* para_code = (const float*)d_in[1];  // (4,256)
  const float* W_c       = (const float*)d_in[2];  // (256,256)
  const float* b_c       = (const float*)d_in[3];  // (256,)
  const float* W_s       = (const float*)d_in[4];  // (256,256)
  const float* b_s       = (const float*)d_in[5];  // (256,)
  const float* W_r       = (const float*)d_in[6];  // (256,256)
  const float* b_r       = (const float*)d_in[7];  // (256,)
  const float* W_t       = (const float*)d_in[8];  // (256,512)
  const float* b_t       = (const float*)d_in[9];  // (512,)
  float* out = (float*)d_out;
  float4* par = (float4*)d_ws;  // 1024 float4 = 16 KB

  adaat_params_kernel<<<32, 256, 0, stream>>>(
      para_code, W_c, b_c, W_s, b_s, W_r, b_r, W_t, b_t, par);
  adaat_main_kernel<<<512, 256, 0, stream>>>(fm, par, out);
}

// Round 8
// 100.788 us; speedup vs baseline: 1.0783x; 1.0783x over previous
//
#include <hip/hip_runtime.h>
#include <math.h>

#define PI_F 3.14159f
#define STRD 69            // row stride: 66 used cols (-1..65 -> slots 0..66) + pad
#define SLICE3 (67 * 69)   // 67 rows (y=-1..65) * stride

typedef float f4 __attribute__((ext_vector_type(4)));  // for nontemporal stores

// One fused kernel: 512 blocks x 256 thr. Block = (b, d-pair), XCD-remapped.
//   1. prefetch 3 z-slices HBM -> regs (in flight during GEMV)
//   2. zero LDS guard rings
//   3. p = relu(pc @ W_c + b_c), split-K over 4 waves (overlaps slice drain)
//   4. ds_write slices 0,1; barrier; heads; barrier
//   5. sample plane 0 (slices 0,1), NT stores
//   6. ds_write slice 2 (overlaps plane-0 store drain); barrier
//   7. sample plane 1 (slices slB, slB+1), NT stores
__global__ __launch_bounds__(256, 2) void adaat_fused_kernel(
    const float* __restrict__ fm,
    const float* __restrict__ para_code,
    const float* __restrict__ W_c, const float* __restrict__ b_c,
    const float* __restrict__ W_s, const float* __restrict__ b_s,
    const float* __restrict__ W_r, const float* __restrict__ b_r,
    const float* __restrict__ W_t, const float* __restrict__ b_t,
    float* __restrict__ out) {
  const int i = blockIdx.x;
  const int bid = ((i & 7) << 6) | (i >> 3);  // XCD-contiguous remap
  const int b = bid >> 7;
  const int d0 = (bid & 127) << 1;
  const int d1 = d0 + 1;
  const int tid = threadIdx.x;

  __shared__ float sm[3 * SLICE3];  // 54.2 KB guard-ring slices
  __shared__ float redp[4][256];    // GEMV split-K partials
  __shared__ float red[4][8];
  __shared__ float prm[2][5];       // per plane: sc*32*{co,si}, t*32+31.5 folded below

  // ---- z geometry (exact reference formula sequence) ----
  float gz0 = 2.0f * (d0 * (1.0f / 255.0f)) - 1.0f;
  float izA = ((gz0 + 1.0f) * 256.0f - 1.0f) * 0.5f;
  float z0fA = floorf(izA);
  float wzA = izA - z0fA;
  int zA = (int)z0fA;
  float gz1 = 2.0f * (d1 * (1.0f / 255.0f)) - 1.0f;
  float izB = ((gz1 + 1.0f) * 256.0f - 1.0f) * 0.5f;
  float z0fB = floorf(izB);
  float wzB = izB - z0fB;
  int zB = (int)z0fB;
  int slB = zB - zA;  // ==1 for all even d0 (proven); guard anyway
  if (slB > 1) slB = 1;
  if (slB < 0) slB = 0;

  // ---- 1. prefetch 3 slices into registers ----
  float4 pre[3][4];
  const float4* fmb = (const float4*)(fm + ((size_t)b << 20));
#pragma unroll
  for (int s = 0; s < 3; ++s) {
    int z = zA + s;
    if ((unsigned)z < 256u) {  // block-uniform branch
      const float4* src = fmb + ((size_t)z << 10);
#pragma unroll
      for (int k = 0; k < 4; ++k) pre[s][k] = src[(k << 8) + tid];
    } else {
#pragma unroll
      for (int k = 0; k < 4; ++k) pre[s][k] = make_float4(0.f, 0.f, 0.f, 0.f);
    }
  }

  // ---- 2. zero guard rings (no vmcnt dependency) ----
#pragma unroll
  for (int s = 0; s < 3; ++s) {
    float* smb = sm + s * SLICE3;
    if (tid < STRD) {
      smb[tid] = 0.0f;
      smb[65 * STRD + tid] = 0.0f;
      smb[66 * STRD + tid] = 0.0f;
    }
    int r = 1 + (tid >> 2);
    int q = tid & 3;
    int c = q ? (64 + q) : 0;
    smb[r * STRD + c] = 0.0f;
  }

  // ---- 3. GEMV p = relu(pc @ W_c + b_c), split-K over waves ----
  {
    const int wv = tid >> 6, ln = tid & 63;
    const float* pcb = para_code + (b << 8);
    float pcv = pcb[(wv << 6) | ln];
    float4 a4 = make_float4(0.f, 0.f, 0.f, 0.f);
#pragma unroll
    for (int kk = 0; kk < 64; ++kk) {
      float pk = __int_as_float(
          __builtin_amdgcn_readlane(__float_as_int(pcv), kk));
      const float4* Wrow = (const float4*)(W_c + (((wv << 6) + kk) << 8));
      float4 w4 = Wrow[ln];
      a4.x = fmaf(pk, w4.x, a4.x);
      a4.y = fmaf(pk, w4.y, a4.y);
      a4.z = fmaf(pk, w4.z, a4.z);
      a4.w = fmaf(pk, w4.w, a4.w);
    }
    ((float4*)&redp[wv][0])[ln] = a4;
  }

  // ---- 4a. stage slices 0,1 (loads drained under GEMV) ----
#pragma unroll
  for (int s = 0; s < 2; ++s) {
    float* smb = sm + s * SLICE3;
#pragma unroll
    for (int k = 0; k < 4; ++k) {
      int e = ((k << 8) + tid) << 2;
      int y = e >> 6, x0 = e & 63;
      int a = (y + 1) * STRD + x0 + 1;
      float4 v = pre[s][k];
      smb[a] = v.x; smb[a + 1] = v.y; smb[a + 2] = v.z; smb[a + 3] = v.w;
    }
  }
  __syncthreads();  // covers sm slices 0,1 and redp

  // ---- 4b. heads: 8 dot-products (2 planes x {s,r,t0,t1}) ----
  {
    float pk = fmaxf(redp[0][tid] + redp[1][tid] + redp[2][tid] +
                         redp[3][tid] + b_c[tid],
                     0.0f);
    float2 ws = *(const float2*)(W_s + (tid << 8) + d0);
    float2 wr = *(const float2*)(W_r + (tid << 8) + d0);
    float4 wt = *(const float4*)(W_t + (tid << 9) + (d0 << 1));
    float v0 = pk * ws.x, v1 = pk * ws.y;
    float v2 = pk * wr.x, v3 = pk * wr.y;
    float v4 = pk * wt.x, v5 = pk * wt.z;
    float v6 = pk * wt.y, v7 = pk * wt.w;
#pragma unroll
    for (int off = 32; off > 0; off >>= 1) {
      v0 += __shfl_xor(v0, off);
      v1 += __shfl_xor(v1, off);
      v2 += __shfl_xor(v2, off);
      v3 += __shfl_xor(v3, off);
      v4 += __shfl_xor(v4, off);
      v5 += __shfl_xor(v5, off);
      v6 += __shfl_xor(v6, off);
      v7 += __shfl_xor(v7, off);
    }
    int wv = tid >> 6;
    if ((tid & 63) == 0) {
      red[wv][0] = v0; red[wv][1] = v1; red[wv][2] = v2; red[wv][3] = v3;
      red[wv][4] = v4; red[wv][5] = v5; red[wv][6] = v6; red[wv][7] = v7;
    }
  }
  __syncthreads();
  if (tid < 8) {
    float v = red[0][tid] + red[1][tid] + red[2][tid] + red[3][tid];
    int pl = tid & 1;
    int dsel = d0 + pl;
    int typ = tid >> 1;  // 0:scale 1:rot 2:t0 3:t1
    if (typ == 0) {
      v += b_s[dsel];
      prm[pl][0] = 2.0f / (1.0f + expf(-v));
    } else if (typ == 1) {
      v += b_r[dsel];
      float ang = tanhf(v) * PI_F;
      prm[pl][1] = cosf(ang);
      prm[pl][2] = sinf(ang);
    } else if (typ == 2) {
      v += b_t[2 * dsel];
      prm[pl][3] = tanhf(v);
    } else {
      v += b_t[2 * dsel + 1];
      prm[pl][4] = tanhf(v);
    }
  }
  __syncthreads();

  // ---- 5/6/7. sample plane 0, stage slice 2, sample plane 1 ----
  const float dgx = 2.0f / 63.0f;
  const int w0 = (tid & 15) << 2;
  const int h0 = tid >> 4;
  const float gx0 = w0 * dgx - 1.0f;

#pragma unroll
  for (int pl = 0; pl < 2; ++pl) {
    const float sc = prm[pl][0];
    const float co = prm[pl][1];
    const float si = prm[pl][2];
    const float t0 = prm[pl][3];
    const float t1 = prm[pl][4];
    const float wz = pl ? wzB : wzA;
    const float wzl0 = 1.0f - wz, wzl1 = wz;
    const float* smA = sm + ((pl ? slB : 0) * SLICE3);
    const float* smB = smA + SLICE3;
    float* outp = out + (((size_t)(b << 8) + d0 + pl) << 12);

    const float co32 = co * sc * 32.0f;
    const float si32 = si * sc * 32.0f;
    const float stx = co32 * dgx;
    const float sty = si32 * dgx;
    const float ixw = fmaf(co32, gx0, fmaf(t0, 32.0f, 31.5f));
    const float iyw = fmaf(si32, gx0, fmaf(t1, 32.0f, 31.5f));

#pragma unroll
    for (int j = 0; j < 4; ++j) {
      int h = (j << 4) + h0;
      float gy = h * dgx - 1.0f;
      float ix = fmaf(-si32, gy, ixw);
      float iy = fmaf(co32, gy, iyw);
      float rr[4];
#pragma unroll
      for (int q = 0; q < 4; ++q) {
        float x0f = floorf(ix), y0f = floorf(iy);
        float wx = ix - x0f, wy = iy - y0f;
        int xi = (int)x0f, yi = (int)y0f;
        int bx = min(max(xi, -1), 64);  // v_med3_i32
        int by = min(max(yi, -1), 64);
        float wxe = (bx == xi) ? wx : 0.0f;
        float wye = (by == yi) ? wy : 0.0f;
        float w11 = wye * wxe;
        float w10 = wye - w11;
        float w01 = wxe - w11;
        float w00 = (1.0f - wye) - w01;
        int base = (by + 1) * STRD + bx + 1;
        float accA = fmaf(smA[base], w00,
                     fmaf(smA[base + 1], w01,
                     fmaf(smA[base + STRD], w10, smA[base + STRD + 1] * w11)));
        float accB = fmaf(smB[base], w00,
                     fmaf(smB[base + 1], w01,
                     fmaf(smB[base + STRD], w10, smB[base + STRD + 1] * w11)));
        rr[q] = fmaf(wzl0, accA, wzl1 * accB);
        ix += stx;
        iy += sty;
      }
      f4 res;
      res.x = rr[0]; res.y = rr[1]; res.z = rr[2]; res.w = rr[3];
      __builtin_nontemporal_store(res, (f4*)outp + (j << 8) + tid);
    }

    if (pl == 0) {
      // stage slice 2 now; overlaps plane-0 NT-store drain. Plane-0 reads
      // touched only slice-0/1 regions, so no barrier needed before writes.
      float* smb = sm + 2 * SLICE3;
#pragma unroll
      for (int k = 0; k < 4; ++k) {
        int e = ((k << 8) + tid) << 2;
        int y = e >> 6, x0 = e & 63;
        int a = (y + 1) * STRD + x0 + 1;
        float4 v = pre[2][k];
        smb[a] = v.x; smb[a + 1] = v.y; smb[a + 2] = v.z; smb[a + 3] = v.w;
      }
      __syncthreads();
    }
  }
}

extern "C" void kernel_launch(void* const* d_in, const int* in_sizes, int n_in,
                              void* d_out, int out_size, void* d_ws, size_t ws_size,
                              hipStream_t stream) {
  const float* fm        = (const float*)d_in[0];  // (4,256,64,64)
  const float* para_code = (const float*)d_in[1];  // (4,256)
  const float* W_c       = (const float*)d_in[2];  // (256,256)
  const float* b_c       = (const float*)d_in[3];  // (256,)
  const float* W_s       = (const float*)d_in[4];  // (256,256)
  const float* b_s       = (const float*)d_in[5];  // (256,)
  const float* W_r       = (const float*)d_in[6];  // (256,256)
  const float* b_r       = (const float*)d_in[7];  // (256,)
  const float* W_t       = (const float*)d_in[8];  // (256,512)
  const float* b_t       = (const float*)d_in[9];  // (512,)
  float* out = (float*)d_out;

  adaat_fused_kernel<<<512, 256, 0, stream>>>(
      fm, para_code, W_c, b_c, W_s, b_s, W_r, b_r, W_t, b_t, out);
}